// Round 7
// baseline (130.701 us; speedup 1.0000x reference)
//
#include <hip/hip_runtime.h>
#include <math.h>

#define BB 32
#define TT 4096
#define HH 512
#define QQS 512
#define WCH 32           // rows per wave
#define NCH (TT / WCH)   // 128 chunks per batch

#define TANH_K 2.8853900817779268f   // 2*log2(e)
#define LOG2E  1.4426950408889634f

__device__ inline float fast_exp2(float x) {
#if __has_builtin(__builtin_amdgcn_exp2f)
    return __builtin_amdgcn_exp2f(x);
#else
    return exp2f(x);
#endif
}
__device__ inline float fast_rcp(float x) {
#if __has_builtin(__builtin_amdgcn_rcpf)
    return __builtin_amdgcn_rcpf(x);
#else
    return 1.f / x;
#endif
}

__device__ inline float wave_reduce_sum(float v) {
#pragma unroll
    for (int off = 32; off > 0; off >>= 1) v += __shfl_xor(v, off, 64);
    return v;
}

// q[b][h] = sum_s query[b][s] * Wq[h][s]; one wave per (b,h)
__global__ void qproj_kernel(const float* __restrict__ query,
                             const float* __restrict__ Wq,
                             float* __restrict__ qout) {
    int wid  = (blockIdx.x * blockDim.x + threadIdx.x) >> 6;
    int lane = threadIdx.x & 63;
    int b = wid >> 9;        // / HH
    int h = wid & (HH - 1);
    const float4* qr = (const float4*)(query + (size_t)b * QQS);
    const float4* wr = (const float4*)(Wq + (size_t)h * QQS);
    float4 a0 = qr[lane],      w0 = wr[lane];
    float4 a1 = qr[lane + 64], w1 = wr[lane + 64];
    float acc = a0.x * w0.x + a0.y * w0.y + a0.z * w0.z + a0.w * w0.w
              + a1.x * w1.x + a1.y * w1.y + a1.z * w1.z + a1.w * w1.w;
    acc = wave_reduce_sum(acc);
    if (lane == 0) qout[wid] = acc;
}

// tanh contribution: th = 1 - 2*rcp(exp2(k*K + qc) + 1); p += th * w
__device__ __forceinline__ float tanh_term(float k, float qc, float w, float p) {
    float e = fast_exp2(fmaf(k, TANH_K, qc));
    float r = fast_rcp(e + 1.f);
    float th = fmaf(-2.f, r, 1.f);
    return fmaf(th, w, p);
}

struct Buf {
    float4 k0a, k0b, k1a, k1b;
    float4 v0a, v0b, v1a, v1b;
};

__device__ __forceinline__ void load_pair(const float4* kb4, const float4* vb4,
                                          int p, int lane, Buf& B) {
    const float4* kp0 = kb4 + (size_t)(2 * p)     * (HH / 4);
    const float4* kp1 = kb4 + (size_t)(2 * p + 1) * (HH / 4);
    const float4* vp0 = vb4 + (size_t)(2 * p)     * (HH / 4);
    const float4* vp1 = vb4 + (size_t)(2 * p + 1) * (HH / 4);
    B.k0a = kp0[lane]; B.k0b = kp0[lane + 64];
    B.k1a = kp1[lane]; B.k1b = kp1[lane + 64];
    B.v0a = vp0[lane]; B.v0b = vp0[lane + 64];
    B.v1a = vp1[lane]; B.v1b = vp1[lane + 64];
}

__device__ __forceinline__ void comp_pair(const Buf& B, int p, int lane,
                                          const float4& q0, const float4& q1,
                                          const float4& w0, const float4& w1,
                                          float4& accA, float4& accB,
                                          float& z, float& ev) {
    float p0 = 0.f, p1 = 0.f;
    p0 = tanh_term(B.k0a.x, q0.x, w0.x, p0);
    p0 = tanh_term(B.k0a.y, q0.y, w0.y, p0);
    p0 = tanh_term(B.k0a.z, q0.z, w0.z, p0);
    p0 = tanh_term(B.k0a.w, q0.w, w0.w, p0);
    p0 = tanh_term(B.k0b.x, q1.x, w1.x, p0);
    p0 = tanh_term(B.k0b.y, q1.y, w1.y, p0);
    p0 = tanh_term(B.k0b.z, q1.z, w1.z, p0);
    p0 = tanh_term(B.k0b.w, q1.w, w1.w, p0);
    p1 = tanh_term(B.k1a.x, q0.x, w0.x, p1);
    p1 = tanh_term(B.k1a.y, q0.y, w0.y, p1);
    p1 = tanh_term(B.k1a.z, q0.z, w0.z, p1);
    p1 = tanh_term(B.k1a.w, q0.w, w0.w, p1);
    p1 = tanh_term(B.k1b.x, q1.x, w1.x, p1);
    p1 = tanh_term(B.k1b.y, q1.y, w1.y, p1);
    p1 = tanh_term(B.k1b.z, q1.z, w1.z, p1);
    p1 = tanh_term(B.k1b.w, q1.w, w1.w, p1);

    // paired reduce: lanes<32 carry sum(p0), lanes>=32 carry sum(p1)
    float a0 = __shfl_xor(p0, 32, 64);
    float a1 = __shfl_xor(p1, 32, 64);
    float ws = (lane < 32) ? (p0 + a0) : (p1 + a1);
#pragma unroll
    for (int off = 16; off > 0; off >>= 1) ws += __shfl_xor(ws, off, 64);
    float s0 = __shfl(ws, 0, 64);
    float s1 = __shfl(ws, 32, 64);

    float e0 = fast_exp2(s0 * LOG2E);
    float e1 = fast_exp2(s1 * LOG2E);
    z += e0 + e1;
    ev = (lane == 2 * p)     ? e0 : ev;
    ev = (lane == 2 * p + 1) ? e1 : ev;

    accA.x = fmaf(e0, B.v0a.x, accA.x); accA.y = fmaf(e0, B.v0a.y, accA.y);
    accA.z = fmaf(e0, B.v0a.z, accA.z); accA.w = fmaf(e0, B.v0a.w, accA.w);
    accB.x = fmaf(e0, B.v0b.x, accB.x); accB.y = fmaf(e0, B.v0b.y, accB.y);
    accB.z = fmaf(e0, B.v0b.z, accB.z); accB.w = fmaf(e0, B.v0b.w, accB.w);
    accA.x = fmaf(e1, B.v1a.x, accA.x); accA.y = fmaf(e1, B.v1a.y, accA.y);
    accA.z = fmaf(e1, B.v1a.z, accA.z); accA.w = fmaf(e1, B.v1a.w, accA.w);
    accB.x = fmaf(e1, B.v1b.x, accB.x); accB.y = fmaf(e1, B.v1b.y, accB.y);
    accB.z = fmaf(e1, B.v1b.z, accB.z); accB.w = fmaf(e1, B.v1b.w, accB.w);
}

// Fused, wave-independent, software-pipelined. Each wave owns WCH rows:
// 2-deep register double-buffer over row pairs, e=exp(s) immediately (no max;
// |s| <= ||We||_1 ~ 18 so exp(s) is safely in f32 range). No LDS, no barriers.
__global__ __launch_bounds__(256) void fused_kernel(
        const float* __restrict__ key, const float* __restrict__ value,
        const float* __restrict__ qb,  const float* __restrict__ We,
        float* __restrict__ alphas, float* __restrict__ zbuf,
        float* __restrict__ part) {
    int tid = threadIdx.x, w = tid >> 6, lane = tid & 63;
    int b = blockIdx.x >> 5;                  // 32 blocks per batch
    int c = ((blockIdx.x & 31) << 2) | w;     // chunk 0..127
    size_t row0 = (size_t)b * TT + (size_t)c * WCH;

    const float4* qv = (const float4*)(qb + (size_t)b * HH);
    const float4* wv = (const float4*)We;
    float4 q0 = qv[lane], q1 = qv[lane + 64];
    float4 w0 = wv[lane], w1 = wv[lane + 64];
    q0.x *= TANH_K; q0.y *= TANH_K; q0.z *= TANH_K; q0.w *= TANH_K;
    q1.x *= TANH_K; q1.y *= TANH_K; q1.z *= TANH_K; q1.w *= TANH_K;

    const float4* kb4 = (const float4*)(key + row0 * HH);
    const float4* vb4 = (const float4*)(value + row0 * HH);

    float4 accA = make_float4(0.f, 0.f, 0.f, 0.f);
    float4 accB = make_float4(0.f, 0.f, 0.f, 0.f);
    float z = 0.f, ev = 0.f;

    Buf X, Y;
    load_pair(kb4, vb4, 0, lane, X);
    load_pair(kb4, vb4, 1, lane, Y);
#pragma unroll
    for (int p = 0; p < 14; p += 2) {
        comp_pair(X, p, lane, q0, q1, w0, w1, accA, accB, z, ev);
        load_pair(kb4, vb4, p + 2, lane, X);
        comp_pair(Y, p + 1, lane, q0, q1, w0, w1, accA, accB, z, ev);
        load_pair(kb4, vb4, p + 3, lane, Y);
    }
    comp_pair(X, 14, lane, q0, q1, w0, w1, accA, accB, z, ev);
    comp_pair(Y, 15, lane, q0, q1, w0, w1, accA, accB, z, ev);

    // outputs: raw e for rows (lanes 0..31), chunk z, partial ctx
    if (lane < WCH) alphas[row0 + lane] = ev;
    if (lane == 0) zbuf[b * NCH + c] = z;
    float4* pp = (float4*)(part + ((size_t)c * BB + b) * HH);
    pp[lane] = accA;
    pp[lane + 64] = accB;
}

// Finalize: blocks 0..31 -> rescale alphas in place; blocks 32..95 -> context
__global__ void finalize_kernel(const float* __restrict__ zbuf,
                                const float* __restrict__ part,
                                float* __restrict__ alphas,
                                float* __restrict__ ctx) {
    int tid = threadIdx.x, lane = tid & 63;
    int b = (blockIdx.x < BB) ? blockIdx.x : ((blockIdx.x - BB) >> 1);

    // every wave redundantly reduces the 128 chunk-sums (fixed order)
    float z = zbuf[b * NCH + lane] + zbuf[b * NCH + 64 + lane];
    float Z = wave_reduce_sum(z);
    float invZ = fast_rcp(Z);

    if (blockIdx.x < BB) {
        float4* ap = (float4*)(alphas + (size_t)b * TT);
#pragma unroll
        for (int i = 0; i < 4; ++i) {
            int idx = tid + i * 256;
            float4 a = ap[idx];
            a.x *= invZ; a.y *= invZ; a.z *= invZ; a.w *= invZ;
            ap[idx] = a;
        }
    } else {
        int d = ((blockIdx.x - BB) & 1) * 256 + tid;
        float s = 0.f;
#pragma unroll 8
        for (int c2 = 0; c2 < NCH; ++c2)
            s += part[((size_t)c2 * BB + b) * HH + d];
        ctx[(size_t)b * HH + d] = s * invZ;
    }
}

extern "C" void kernel_launch(void* const* d_in, const int* in_sizes, int n_in,
                              void* d_out, int out_size, void* d_ws, size_t ws_size,
                              hipStream_t stream) {
    const float* query = (const float*)d_in[0];
    const float* key   = (const float*)d_in[1];
    const float* value = (const float*)d_in[2];
    // d_in[3] = mask (unused by reference forward)
    const float* Wq    = (const float*)d_in[4];
    const float* We    = (const float*)d_in[5];

    float* ctx    = (float*)d_out;            // [B,1,H]
    float* alphas = (float*)d_out + BB * HH;  // [B,T]

    float* qbuf   = (float*)d_ws;                    // B*H floats
    float* zbuf   = qbuf + BB * HH;                  // B*NCH floats
    float* part   = zbuf + BB * NCH;                 // NCH*B*H floats = 8 MiB

    qproj_kernel<<<(BB * HH) / 4, 256, 0, stream>>>(query, Wq, qbuf);
    fused_kernel<<<BB * 32, 256, 0, stream>>>(key, value, qbuf, We, alphas, zbuf, part);
    finalize_kernel<<<BB + 2 * BB, 256, 0, stream>>>(zbuf, part, alphas, ctx);
}

// Round 8
// 110.653 us; speedup vs baseline: 1.1812x; 1.1812x over previous
//
#include <hip/hip_runtime.h>
#include <math.h>

#define BB 32
#define TT 4096
#define HH 512
#define QQS 512
#define TS 64            // chunks per batch
#define CH 64            // rows per chunk (TS*CH == TT)

#define TANH_K 2.8853900817779268f   // 2*log2(e)
#define LOG2E  1.4426950408889634f

__device__ inline float fast_exp2(float x) {
#if __has_builtin(__builtin_amdgcn_exp2f)
    return __builtin_amdgcn_exp2f(x);
#else
    return exp2f(x);
#endif
}
__device__ inline float fast_rcp(float x) {
#if __has_builtin(__builtin_amdgcn_rcpf)
    return __builtin_amdgcn_rcpf(x);
#else
    return 1.f / x;
#endif
}

__device__ inline float wave_reduce_sum(float v) {
#pragma unroll
    for (int off = 32; off > 0; off >>= 1) v += __shfl_xor(v, off, 64);
    return v;
}

// q[b][h] = sum_s query[b][s] * Wq[h][s]; one wave per (b,h)
__global__ void qproj_kernel(const float* __restrict__ query,
                             const float* __restrict__ Wq,
                             float* __restrict__ qout) {
    int wid  = (blockIdx.x * blockDim.x + threadIdx.x) >> 6;
    int lane = threadIdx.x & 63;
    int b = wid >> 9;        // / HH
    int h = wid & (HH - 1);
    const float4* qr = (const float4*)(query + (size_t)b * QQS);
    const float4* wr = (const float4*)(Wq + (size_t)h * QQS);
    float4 a0 = qr[lane],      w0 = wr[lane];
    float4 a1 = qr[lane + 64], w1 = wr[lane + 64];
    float acc = a0.x * w0.x + a0.y * w0.y + a0.z * w0.z + a0.w * w0.w
              + a1.x * w1.x + a1.y * w1.y + a1.z * w1.z + a1.w * w1.w;
    acc = wave_reduce_sum(acc);
    if (lane == 0) qout[wid] = acc;
}

// tanh contribution: th = 1 - 2*rcp(exp2(k*K + qc) + 1); p += th * w
__device__ __forceinline__ float tanh_term(float k, float qc, float w, float p) {
    float e = fast_exp2(fmaf(k, TANH_K, qc));
    float r = fast_rcp(e + 1.f);
    float th = fmaf(-2.f, r, 1.f);
    return fmaf(th, w, p);
}

// Fused: per (b,chunk) block. Phase A: 4 waves stream the key chunk
// contiguously, compute e=exp(s) inline (no max; |s|<=||We||_1~18, safe in
// f32), stash e in LDS. ONE barrier. Phase C: all 256 threads stream the
// value chunk contiguously (float2/thread), accumulate e-weighted partial
// context in registers; wave 0 also emits alphas (raw e) and chunk z.
__global__ __launch_bounds__(256) void fused_kernel(
        const float* __restrict__ key, const float* __restrict__ value,
        const float* __restrict__ qb,  const float* __restrict__ We,
        float* __restrict__ alphas, float* __restrict__ zbuf,
        float* __restrict__ part) {
    __shared__ float e_lds[CH];

    int b = blockIdx.x / TS, c = blockIdx.x % TS;
    int tid = threadIdx.x, w = tid >> 6, lane = tid & 63;
    size_t row0 = (size_t)b * TT + (size_t)c * CH;

    const float4* qv = (const float4*)(qb + (size_t)b * HH);
    const float4* wv = (const float4*)We;
    float4 q0 = qv[lane], q1 = qv[lane + 64];
    float4 w0 = wv[lane], w1 = wv[lane + 64];
    q0.x *= TANH_K; q0.y *= TANH_K; q0.z *= TANH_K; q0.w *= TANH_K;
    q1.x *= TANH_K; q1.y *= TANH_K; q1.z *= TANH_K; q1.w *= TANH_K;

    const float4* kb4 = (const float4*)(key + row0 * HH);

    // Phase A: wave w does row pairs {rr*8+w, rr*8+w+4}, rr=0..7
#pragma unroll 2
    for (int rr = 0; rr < CH / 8; ++rr) {
        int r0 = rr * 8 + w, r1 = r0 + 4;
        const float4* kp0 = kb4 + (size_t)r0 * (HH / 4);
        const float4* kp1 = kb4 + (size_t)r1 * (HH / 4);
        float4 ka = kp0[lane], kb_ = kp0[lane + 64];
        float4 kc = kp1[lane], kd = kp1[lane + 64];
        float p0 = 0.f, p1 = 0.f;
        p0 = tanh_term(ka.x, q0.x, w0.x, p0);
        p0 = tanh_term(ka.y, q0.y, w0.y, p0);
        p0 = tanh_term(ka.z, q0.z, w0.z, p0);
        p0 = tanh_term(ka.w, q0.w, w0.w, p0);
        p0 = tanh_term(kb_.x, q1.x, w1.x, p0);
        p0 = tanh_term(kb_.y, q1.y, w1.y, p0);
        p0 = tanh_term(kb_.z, q1.z, w1.z, p0);
        p0 = tanh_term(kb_.w, q1.w, w1.w, p0);
        p1 = tanh_term(kc.x, q0.x, w0.x, p1);
        p1 = tanh_term(kc.y, q0.y, w0.y, p1);
        p1 = tanh_term(kc.z, q0.z, w0.z, p1);
        p1 = tanh_term(kc.w, q0.w, w0.w, p1);
        p1 = tanh_term(kd.x, q1.x, w1.x, p1);
        p1 = tanh_term(kd.y, q1.y, w1.y, p1);
        p1 = tanh_term(kd.z, q1.z, w1.z, p1);
        p1 = tanh_term(kd.w, q1.w, w1.w, p1);
        // paired reduce: lanes<32 -> sum(p0) [row r0], lanes>=32 -> sum(p1)
        float a0 = __shfl_xor(p0, 32, 64);
        float a1 = __shfl_xor(p1, 32, 64);
        float ws = (lane < 32) ? (p0 + a0) : (p1 + a1);
#pragma unroll
        for (int off = 16; off > 0; off >>= 1) ws += __shfl_xor(ws, off, 64);
        if ((lane & 31) == 0)
            e_lds[(lane < 32) ? r0 : r1] = fast_exp2(ws * LOG2E);
    }
    __syncthreads();

    // wave 0: alphas (raw e) + chunk z, while others start phase C
    if (w == 0) {
        float e = e_lds[lane];
        alphas[row0 + lane] = e;
        float zz = wave_reduce_sum(e);
        if (lane == 0) zbuf[b * TS + c] = zz;
    }

    // Phase C: 256 threads, float2 per thread, stream value chunk rows
    const float2* vb2 = (const float2*)(value + row0 * HH);
    float2 acc = make_float2(0.f, 0.f);
#pragma unroll 8
    for (int r = 0; r < CH; ++r) {
        float e = e_lds[r];
        float2 v = vb2[(size_t)r * (HH / 2) + tid];
        acc.x = fmaf(e, v.x, acc.x);
        acc.y = fmaf(e, v.y, acc.y);
    }
    ((float2*)(part + ((size_t)c * BB + b) * HH))[tid] = acc;
}

// Finalize: blocks 0..31 -> rescale alphas in place; blocks 32..95 -> context
__global__ void finalize_kernel(const float* __restrict__ zbuf,
                                const float* __restrict__ part,
                                float* __restrict__ alphas,
                                float* __restrict__ ctx) {
    int tid = threadIdx.x, lane = tid & 63;
    int b = (blockIdx.x < BB) ? blockIdx.x : ((blockIdx.x - BB) >> 1);

    // every wave redundantly reduces the 64 chunk-sums (fixed order)
    float z = zbuf[b * TS + lane];
    float Z = wave_reduce_sum(z);
    float invZ = fast_rcp(Z);

    if (blockIdx.x < BB) {
        float4* ap = (float4*)(alphas + (size_t)b * TT);
#pragma unroll
        for (int i = 0; i < 4; ++i) {
            int idx = tid + i * 256;
            float4 a = ap[idx];
            a.x *= invZ; a.y *= invZ; a.z *= invZ; a.w *= invZ;
            ap[idx] = a;
        }
    } else {
        int d = ((blockIdx.x - BB) & 1) * 256 + tid;
        float s = 0.f;
#pragma unroll 8
        for (int c2 = 0; c2 < TS; ++c2)
            s += part[((size_t)c2 * BB + b) * HH + d];
        ctx[(size_t)b * HH + d] = s * invZ;
    }
}

extern "C" void kernel_launch(void* const* d_in, const int* in_sizes, int n_in,
                              void* d_out, int out_size, void* d_ws, size_t ws_size,
                              hipStream_t stream) {
    const float* query = (const float*)d_in[0];
    const float* key   = (const float*)d_in[1];
    const float* value = (const float*)d_in[2];
    // d_in[3] = mask (unused by reference forward)
    const float* Wq    = (const float*)d_in[4];
    const float* We    = (const float*)d_in[5];

    float* ctx    = (float*)d_out;            // [B,1,H]
    float* alphas = (float*)d_out + BB * HH;  // [B,T]

    float* qbuf   = (float*)d_ws;                    // B*H floats
    float* zbuf   = qbuf + BB * HH;                  // B*TS floats
    float* part   = zbuf + BB * TS;                  // TS*B*H floats = 4 MiB

    qproj_kernel<<<(BB * HH) / 4, 256, 0, stream>>>(query, Wq, qbuf);
    fused_kernel<<<BB * TS, 256, 0, stream>>>(key, value, qbuf, We, alphas, zbuf, part);
    finalize_kernel<<<BB + 2 * BB, 256, 0, stream>>>(zbuf, part, alphas, ctx);
}

// Round 9
// 109.293 us; speedup vs baseline: 1.1959x; 1.0124x over previous
//
#include <hip/hip_runtime.h>
#include <math.h>

#define BB 32
#define TT 4096
#define HH 512
#define QQS 512
#define TS 64            // chunks per batch
#define CH 64            // rows per chunk (TS*CH == TT)

#define TANH_K 2.8853900817779268f   // 2*log2(e)
#define LOG2E  1.4426950408889634f

__device__ inline float fast_exp2(float x) {
#if __has_builtin(__builtin_amdgcn_exp2f)
    return __builtin_amdgcn_exp2f(x);
#else
    return exp2f(x);
#endif
}
__device__ inline float fast_rcp(float x) {
#if __has_builtin(__builtin_amdgcn_rcpf)
    return __builtin_amdgcn_rcpf(x);
#else
    return 1.f / x;
#endif
}

__device__ inline float wave_reduce_sum(float v) {
#pragma unroll
    for (int off = 32; off > 0; off >>= 1) v += __shfl_xor(v, off, 64);
    return v;
}

// q[b][h] = sum_s query[b][s] * Wq[h][s]; one wave per (b,h)
__global__ void qproj_kernel(const float* __restrict__ query,
                             const float* __restrict__ Wq,
                             float* __restrict__ qout) {
    int wid  = (blockIdx.x * blockDim.x + threadIdx.x) >> 6;
    int lane = threadIdx.x & 63;
    int b = wid >> 9;        // / HH
    int h = wid & (HH - 1);
    const float4* qr = (const float4*)(query + (size_t)b * QQS);
    const float4* wr = (const float4*)(Wq + (size_t)h * QQS);
    float4 a0 = qr[lane],      w0 = wr[lane];
    float4 a1 = qr[lane + 64], w1 = wr[lane + 64];
    float acc = a0.x * w0.x + a0.y * w0.y + a0.z * w0.z + a0.w * w0.w
              + a1.x * w1.x + a1.y * w1.y + a1.z * w1.z + a1.w * w1.w;
    acc = wave_reduce_sum(acc);
    if (lane == 0) qout[wid] = acc;
}

// tanh contribution: th = 1 - 2*rcp(exp2(k*K + qc) + 1); p += th * w
__device__ __forceinline__ float tanh_term(float k, float qc, float w, float p) {
    float e = fast_exp2(fmaf(k, TANH_K, qc));
    float r = fast_rcp(e + 1.f);
    float th = fmaf(-2.f, r, 1.f);
    return fmaf(th, w, p);
}

// Fused: per (b,chunk) block. Phase A: 4 waves stream key chunk contiguously,
// e=exp(s) inline (no max; |s|<=||We||_1~18, f32-safe), e -> LDS. Value row
// prefetched pre-barrier. Phase C: float4/thread over rows rg,rg+2,...;
// 2-way LDS combine. Wave 0 emits alphas (raw e) + chunk z post-barrier.
__global__ __launch_bounds__(256) void fused_kernel(
        const float* __restrict__ key, const float* __restrict__ value,
        const float* __restrict__ qb,  const float* __restrict__ We,
        float* __restrict__ alphas, float* __restrict__ zbuf,
        float* __restrict__ part) {
    __shared__ float e_lds[CH];
    __shared__ float4 ctx_lds[HH / 4];

    int b = blockIdx.x / TS, c = blockIdx.x % TS;
    int tid = threadIdx.x, w = tid >> 6, lane = tid & 63;
    size_t row0 = (size_t)b * TT + (size_t)c * CH;

    const float4* qv = (const float4*)(qb + (size_t)b * HH);
    const float4* wv = (const float4*)We;
    float4 q0 = qv[lane], q1 = qv[lane + 64];
    float4 w0 = wv[lane], w1 = wv[lane + 64];
    q0.x *= TANH_K; q0.y *= TANH_K; q0.z *= TANH_K; q0.w *= TANH_K;
    q1.x *= TANH_K; q1.y *= TANH_K; q1.z *= TANH_K; q1.w *= TANH_K;

    const float4* kb4 = (const float4*)(key + row0 * HH);
    const float4* vb4 = (const float4*)(value + row0 * HH);
    int d4 = tid & 127, rg = tid >> 7;

    // Phase A: wave w does row pairs {rr*8+w, rr*8+w+4}, rr=0..7
#pragma unroll 2
    for (int rr = 0; rr < CH / 8; ++rr) {
        int r0 = rr * 8 + w, r1 = r0 + 4;
        const float4* kp0 = kb4 + (size_t)r0 * (HH / 4);
        const float4* kp1 = kb4 + (size_t)r1 * (HH / 4);
        float4 ka = kp0[lane], kb_ = kp0[lane + 64];
        float4 kc = kp1[lane], kd = kp1[lane + 64];
        float p0 = 0.f, p1 = 0.f;
        p0 = tanh_term(ka.x, q0.x, w0.x, p0);
        p0 = tanh_term(ka.y, q0.y, w0.y, p0);
        p0 = tanh_term(ka.z, q0.z, w0.z, p0);
        p0 = tanh_term(ka.w, q0.w, w0.w, p0);
        p0 = tanh_term(kb_.x, q1.x, w1.x, p0);
        p0 = tanh_term(kb_.y, q1.y, w1.y, p0);
        p0 = tanh_term(kb_.z, q1.z, w1.z, p0);
        p0 = tanh_term(kb_.w, q1.w, w1.w, p0);
        p1 = tanh_term(kc.x, q0.x, w0.x, p1);
        p1 = tanh_term(kc.y, q0.y, w0.y, p1);
        p1 = tanh_term(kc.z, q0.z, w0.z, p1);
        p1 = tanh_term(kc.w, q0.w, w0.w, p1);
        p1 = tanh_term(kd.x, q1.x, w1.x, p1);
        p1 = tanh_term(kd.y, q1.y, w1.y, p1);
        p1 = tanh_term(kd.z, q1.z, w1.z, p1);
        p1 = tanh_term(kd.w, q1.w, w1.w, p1);
        // paired reduce: lanes<32 -> sum(p0) [row r0], lanes>=32 -> sum(p1)
        float a0 = __shfl_xor(p0, 32, 64);
        float a1 = __shfl_xor(p1, 32, 64);
        float ws = (lane < 32) ? (p0 + a0) : (p1 + a1);
#pragma unroll
        for (int off = 16; off > 0; off >>= 1) ws += __shfl_xor(ws, off, 64);
        if ((lane & 31) == 0)
            e_lds[(lane < 32) ? r0 : r1] = fast_exp2(ws * LOG2E);
    }

    // prefetch this thread's first value row (row rg) before the barrier
    float4 vpre = vb4[(size_t)rg * (HH / 4) + d4];
    __syncthreads();

    // wave 0: alphas (raw e) + chunk z, while others start phase C
    if (w == 0) {
        float e = e_lds[lane];
        alphas[row0 + lane] = e;
        float zz = wave_reduce_sum(e);
        if (lane == 0) zbuf[b * TS + c] = zz;
    }

    // Phase C: rows rg, rg+2, ..., float4 per thread
    float e0 = e_lds[rg];
    float4 acc;
    acc.x = e0 * vpre.x; acc.y = e0 * vpre.y;
    acc.z = e0 * vpre.z; acc.w = e0 * vpre.w;
#pragma unroll 8
    for (int r = rg + 2; r < CH; r += 2) {
        float e = e_lds[r];
        float4 v = vb4[(size_t)r * (HH / 4) + d4];
        acc.x = fmaf(e, v.x, acc.x);
        acc.y = fmaf(e, v.y, acc.y);
        acc.z = fmaf(e, v.z, acc.z);
        acc.w = fmaf(e, v.w, acc.w);
    }
    if (rg == 1) ctx_lds[d4] = acc;
    __syncthreads();
    if (rg == 0) {
        float4 t = ctx_lds[d4];
        acc.x += t.x; acc.y += t.y; acc.z += t.z; acc.w += t.w;
        ((float4*)(part + ((size_t)c * BB + b) * HH))[d4] = acc;
    }
}

// Finalize: blocks 0..31 -> rescale alphas in place; blocks 32..95 -> context
__global__ void finalize_kernel(const float* __restrict__ zbuf,
                                const float* __restrict__ part,
                                float* __restrict__ alphas,
                                float* __restrict__ ctx) {
    int tid = threadIdx.x, lane = tid & 63;
    int b = (blockIdx.x < BB) ? blockIdx.x : ((blockIdx.x - BB) >> 1);

    // every wave redundantly reduces the 64 chunk-sums (fixed order)
    float z = zbuf[b * TS + lane];
    float Z = wave_reduce_sum(z);
    float invZ = fast_rcp(Z);

    if (blockIdx.x < BB) {
        float4* ap = (float4*)(alphas + (size_t)b * TT);
#pragma unroll
        for (int i = 0; i < 4; ++i) {
            int idx = tid + i * 256;
            float4 a = ap[idx];
            a.x *= invZ; a.y *= invZ; a.z *= invZ; a.w *= invZ;
            ap[idx] = a;
        }
    } else {
        int d = ((blockIdx.x - BB) & 1) * 256 + tid;
        float s = 0.f;
#pragma unroll 8
        for (int c2 = 0; c2 < TS; ++c2)
            s += part[((size_t)c2 * BB + b) * HH + d];
        ctx[(size_t)b * HH + d] = s * invZ;
    }
}

extern "C" void kernel_launch(void* const* d_in, const int* in_sizes, int n_in,
                              void* d_out, int out_size, void* d_ws, size_t ws_size,
                              hipStream_t stream) {
    const float* query = (const float*)d_in[0];
    const float* key   = (const float*)d_in[1];
    const float* value = (const float*)d_in[2];
    // d_in[3] = mask (unused by reference forward)
    const float* Wq    = (const float*)d_in[4];
    const float* We    = (const float*)d_in[5];

    float* ctx    = (float*)d_out;            // [B,1,H]
    float* alphas = (float*)d_out + BB * HH;  // [B,T]

    float* qbuf   = (float*)d_ws;                    // B*H floats
    float* zbuf   = qbuf + BB * HH;                  // B*TS floats
    float* part   = zbuf + BB * TS;                  // TS*B*H floats = 4 MiB

    qproj_kernel<<<(BB * HH) / 4, 256, 0, stream>>>(query, Wq, qbuf);
    fused_kernel<<<BB * TS, 256, 0, stream>>>(key, value, qbuf, We, alphas, zbuf, part);
    finalize_kernel<<<BB + 2 * BB, 256, 0, stream>>>(zbuf, part, alphas, ctx);
}